// Round 15
// baseline (2293.909 us; speedup 1.0000x reference)
//
#include <hip/hip_runtime.h>

// PointNet++ SA module: FPS -> ball query -> group -> SharedMLP(3) -> maxpool
// B=8, N=8192, C_IN=64, M=1024, K=64, RADIUS=0.2, MLP=[64,64,128]
//
// R15 structure: software pipeline at kernel granularity.
//   K1: FPS[1,512)   (blocks 0-7)  + ft/w0pad builders (blocks 8-63)
//   K2: FPS[512,1024) (blocks 0-7) + workers for m in [0,512) (blocks 8+)
//   K3: workers for m in [512,1024)
// FPS state (mind[], last winner idx) is saved/restored bit-exactly via d_ws.
// Workers = fused ballq + transposed 2-wave MLP (verified components).

#define B_ 8
#define N_ 8192
#define M_ 1024
#define K_ 64
#define FTW 68  // 3 xyz + 64 feat + 1 pad (row = 272B, 16B aligned)

// ---------------------------------------------------------------------------
// u64-key lexicographic merge via DPP (VALU pipe, no LDS).
// key = (f32bits(val) << 32) | ~idx ; distances >= 0 so f32 bits order as u32.
// max(key) == (val desc, idx asc) — associative, any mixing schedule valid.
// ---------------------------------------------------------------------------
template <int CTRL>
__device__ __forceinline__ unsigned long long dpp_key(unsigned long long k) {
  int lo = __builtin_amdgcn_update_dpp(0, (int)(unsigned int)k, CTRL, 0xF, 0xF, true);
  int hi = __builtin_amdgcn_update_dpp(0, (int)(unsigned int)(k >> 32), CTRL, 0xF, 0xF, true);
  unsigned long long o = ((unsigned long long)(unsigned int)hi << 32) | (unsigned int)lo;
  return o > k ? o : k;
}

// 6-level DPP max (pure VALU), used by the fallback mlp path.
template <int CTRL>
__device__ __forceinline__ float dpp_fmax(float v) {
  int o = __builtin_amdgcn_update_dpp(0, __float_as_int(v), CTRL, 0xF, 0xF, true);
  return fmaxf(v, __int_as_float(o));
}
__device__ __forceinline__ float wave_fmax63(float v) {
  v = dpp_fmax<0xB1>(v);
  v = dpp_fmax<0x4E>(v);
  v = dpp_fmax<0x141>(v);
  v = dpp_fmax<0x140>(v);
  v = dpp_fmax<0x142>(v);
  v = dpp_fmax<0x143>(v);
  return v;
}

// ---------------------------------------------------------------------------
// Shared-memory layouts. FPS needs 128.3KB; worker groups fit inside the same
// union in K2 (so worker blocks can never colocate with an FPS block — the
// per-kernel LDS allocation is uniform and 1 block/CU).
// ---------------------------------------------------------------------------
struct FpsShared {
  float4 pts4[N_];                  // 128 KB point table (w unused)
  unsigned long long cand[2][16];   // parity-buffered row-winner keys
};
struct WorkShared {                 // two independent 128-thread task groups
  float xls[2][64 * FTW];
  int islot[2][64];
  float red[2][2][128];
};
union SMemU {
  FpsShared f;
  WorkShared w;
};

// ---------------------------------------------------------------------------
// FPS stage runner: iterations [i_begin, i_end). R4/R8 schedule (measured
// best of 6 variants): 256 threads (4 waves, 1/SIMD) x 32 points, ONE barrier
// per iteration, parity double-buffered candidates, index in the u64 key.
// Per-iteration nxyz writes (t==0) replace the old end-of-kernel writeback
// (identical bits: coords come from the same pts4 entries).
// State across stages: mind[] saved/loaded as raw f32 (bit-exact), plus the
// last winner index (coords re-derived from the identically-rebuilt pts4).
// Arithmetic identical to reference: unfused f32 sub/mul/add in x,y,z order;
// argmax tie-break = first occurrence (lexicographic val desc, idx asc).
// ---------------------------------------------------------------------------
__device__ void fps_run(const float* __restrict__ xb, float* __restrict__ nxyz_b,
                        float* __restrict__ mind_save, int* __restrict__ last_save,
                        FpsShared& S, int i_begin, int i_end, bool first, int t) {
#pragma clang fp contract(off)
  const int lane = t & 63;
  const int wid = t >> 6;  // 0..3

  for (int n = t; n < N_; n += 256) {
    S.pts4[n] = make_float4(xb[n], xb[N_ + n], xb[2 * N_ + n], 0.f);
  }

  const int base = t * 32;
  float px[32], py[32], pz[32], mind[32];
#pragma unroll
  for (int j = 0; j < 32; ++j) {
    px[j] = xb[base + j];
    py[j] = xb[N_ + base + j];
    pz[j] = xb[2 * N_ + base + j];
  }
  if (first) {
#pragma unroll
    for (int j = 0; j < 32; ++j) mind[j] = 1e10f;
  } else {
    const float4* ms = (const float4*)(mind_save + base);
#pragma unroll
    for (int q = 0; q < 8; ++q) {
      float4 v = ms[q];
      mind[4 * q + 0] = v.x; mind[4 * q + 1] = v.y;
      mind[4 * q + 2] = v.z; mind[4 * q + 3] = v.w;
    }
  }
  float xl = 0.f, yl = 0.f, zl = 0.f;
  if (first) {
    xl = xb[0]; yl = xb[N_]; zl = xb[2 * N_];
    if (t == 0) { nxyz_b[0] = xl; nxyz_b[M_] = yl; nxyz_b[2 * M_] = zl; }
  }
  __syncthreads();
  if (!first) {
    const int lg = *last_save;
    float4 c = S.pts4[lg];  // identical bits to previous stage's winner coords
    xl = c.x; yl = c.y; zl = c.z;
  }

  int lastg = 0;
  for (int i = i_begin; i < i_end; ++i) {
    float bestv = -1.f;
    int bl = 0;  // local index 0..31 (inline-const cndmask)
#pragma unroll
    for (int j = 0; j < 32; ++j) {
      float dx = __fsub_rn(px[j], xl);
      float dy = __fsub_rn(py[j], yl);
      float dz = __fsub_rn(pz[j], zl);
      float d = __fadd_rn(__fadd_rn(__fmul_rn(dx, dx), __fmul_rn(dy, dy)), __fmul_rn(dz, dz));
      float md = fminf(mind[j], d);
      mind[j] = md;
      if (md > bestv) { bestv = md; bl = j; }  // ascending j -> first max kept
    }
    unsigned long long key =
        ((unsigned long long)__float_as_uint(bestv) << 32) | (unsigned int)(~(base + bl));
    key = dpp_key<0xB1>(key);   // quad_perm [1,0,3,2]
    key = dpp_key<0x4E>(key);   // quad_perm [2,3,0,1]
    key = dpp_key<0x141>(key);  // row_half_mirror
    key = dpp_key<0x140>(key);  // row_mirror -> 16-lane-row winner
    if ((lane & 15) == 0) S.cand[i & 1][wid * 4 + (lane >> 4)] = key;
    __syncthreads();
    unsigned long long gk = S.cand[i & 1][lane & 15];
    gk = dpp_key<0xB1>(gk);
    gk = dpp_key<0x4E>(gk);
    gk = dpp_key<0x141>(gk);
    gk = dpp_key<0x140>(gk);
    const int gi = (int)(~(unsigned int)gk);
    float4 cc = S.pts4[gi];  // broadcast ds_read_b128, conflict-free
    if (t == 0) { nxyz_b[i] = cc.x; nxyz_b[M_ + i] = cc.y; nxyz_b[2 * M_ + i] = cc.z; }
    xl = cc.x; yl = cc.y; zl = cc.z;
    lastg = gi;
    // no second barrier: next iteration's leader writes go to the other parity
  }

  if (i_end < M_ && mind_save) {
    float4* ms = (float4*)(mind_save + base);
#pragma unroll
    for (int q = 0; q < 8; ++q)
      ms[q] = make_float4(mind[4 * q + 0], mind[4 * q + 1], mind[4 * q + 2], mind[4 * q + 3]);
    if (t == 0) *last_save = lastg;
  }
}

// ---------------------------------------------------------------------------
// Worker: fused ball-query + transposed group/MLP/maxpool for one (b,m) task,
// executed by a 128-thread group (2 waves). Exact composition of the verified
// R11 ballq (wave 0 only; expanded-form unfused f32 distances, 0.04f, ordered
// first-K via ballot/prefix-popcount, first-hit pad) and the verified R14
// transposed MLP (lane = output channel; weights in VGPRs via vector loads;
// activations in a 64x68 LDS buffer consumed as broadcast ds_read_b128;
// wave w owns rows [32w,32w+32); maxpool folded into running fmaxf + 2x128
// LDS combine). FMA order per output identical to reference. absmax 0.
// ---------------------------------------------------------------------------
__device__ void work_task(
    int b, int m, int t128,
    float* __restrict__ xls, int* __restrict__ islot, float (*__restrict__ red)[128],
    const float* __restrict__ xyz, const float* __restrict__ ft,
    const float* __restrict__ w0pad, const float* __restrict__ nxyz,
    const float* __restrict__ s0, const float* __restrict__ b0,
    const float* __restrict__ w1, const float* __restrict__ s1, const float* __restrict__ b1,
    const float* __restrict__ w2, const float* __restrict__ s2, const float* __restrict__ b2,
    float* __restrict__ out2) {
  const int lane = t128 & 63;
  const int w = t128 >> 6;  // 0..1
  const float cx = nxyz[b * 3 * M_ + m];
  const float cy = nxyz[b * 3 * M_ + M_ + m];
  const float cz = nxyz[b * 3 * M_ + 2 * M_ + m];

  // ---- Phase A: ball query (wave 0 of the group only) ----
  if (w == 0) {
    const float* xb = xyz + b * 3 * N_;
    const float nc = __fadd_rn(__fadd_rn(__fmul_rn(cx, cx), __fmul_rn(cy, cy)), __fmul_rn(cz, cz));
    int cnt = 0;
    int first = 0;
    for (int basei = 0; basei < N_ && cnt < K_; basei += 64) {
      const int n = basei + lane;
      float p_x = xb[n], p_y = xb[N_ + n], p_z = xb[2 * N_ + n];
      float pn = __fadd_rn(__fadd_rn(__fmul_rn(p_x, p_x), __fmul_rn(p_y, p_y)), __fmul_rn(p_z, p_z));
      float dt = __fadd_rn(__fadd_rn(__fmul_rn(cx, p_x), __fmul_rn(cy, p_y)), __fmul_rn(cz, p_z));
      float d2 = __fsub_rn(__fadd_rn(nc, pn), __fmul_rn(2.f, dt));
      bool inr = d2 < 0.04f;
      unsigned long long mk = __ballot(inr);
      if (cnt == 0 && mk != 0ull) first = basei + (__ffsll((long long)mk) - 1);
      int pos = cnt + (int)__popcll(mk & ((1ull << lane) - 1ull));
      if (inr && pos < K_) islot[pos] = n;
      cnt += (int)__popcll(mk);
    }
    if (cnt > K_) cnt = K_;
    if (lane >= cnt) islot[lane] = first;  // pad with first hit (0 if none)
  }
  __syncthreads();

  // ---- stage: thread t128 copies half of row (t128>>1) to LDS ----
  {
    const int row = t128 >> 1;
    const int half = t128 & 1;
    const int nk = islot[row];
    const float4* src = (const float4*)(ft + (size_t)((b << 13) + nk) * FTW);
    float4* dst = (float4*)(xls + row * FTW);
    if (half == 0) {
      float4 v0 = src[0];
      v0.x -= cx; v0.y -= cy; v0.z -= cz;
      dst[0] = v0;
#pragma unroll
      for (int q = 1; q < 8; ++q) dst[q] = src[q];
    } else {
#pragma unroll
      for (int q = 8; q < 17; ++q) dst[q] = src[q];
    }
  }
  __syncthreads();

  const int r0 = w * 32;

  // ---- Layer 0: 67(+pad) -> 64 ; weights in 68 VGPRs ----
  float w0r[FTW];
  {
    const float4* wp = (const float4*)(w0pad + lane * FTW);
#pragma unroll
    for (int q = 0; q < 17; ++q) {
      float4 wv = wp[q];
      w0r[4 * q + 0] = wv.x; w0r[4 * q + 1] = wv.y;
      w0r[4 * q + 2] = wv.z; w0r[4 * q + 3] = wv.w;
    }
  }
  const float s0l = s0[lane], b0l = b0[lane];
  for (int kk = 0; kk < 32; kk += 2) {
    const int k = r0 + kk;
    const float4* rowA = (const float4*)(xls + k * FTW);
    const float4* rowB = (const float4*)(xls + (k + 1) * FTW);
    float aA = 0.f, aB = 0.f;
#pragma unroll
    for (int q = 0; q < 17; ++q) {
      float4 xa = rowA[q];
      float4 xbv = rowB[q];
      aA = fmaf(w0r[4 * q + 0], xa.x, aA);
      aA = fmaf(w0r[4 * q + 1], xa.y, aA);
      aA = fmaf(w0r[4 * q + 2], xa.z, aA);
      aA = fmaf(w0r[4 * q + 3], xa.w, aA);
      aB = fmaf(w0r[4 * q + 0], xbv.x, aB);
      aB = fmaf(w0r[4 * q + 1], xbv.y, aB);
      aB = fmaf(w0r[4 * q + 2], xbv.z, aB);
      aB = fmaf(w0r[4 * q + 3], xbv.w, aB);
    }
    xls[k * FTW + lane] = fmaxf(fmaf(aA, s0l, b0l), 0.f);
    xls[(k + 1) * FTW + lane] = fmaxf(fmaf(aB, s0l, b0l), 0.f);
  }

  // ---- Layer 1: 64 -> 64 ; weights in 64 VGPRs ----
  float w1r[64];
  {
    const float4* wp = (const float4*)(w1 + lane * 64);
#pragma unroll
    for (int q = 0; q < 16; ++q) {
      float4 wv = wp[q];
      w1r[4 * q + 0] = wv.x; w1r[4 * q + 1] = wv.y;
      w1r[4 * q + 2] = wv.z; w1r[4 * q + 3] = wv.w;
    }
  }
  const float s1l = s1[lane], b1l = b1[lane];
  for (int kk = 0; kk < 32; kk += 2) {
    const int k = r0 + kk;
    const float4* rowA = (const float4*)(xls + k * FTW);
    const float4* rowB = (const float4*)(xls + (k + 1) * FTW);
    float aA = 0.f, aB = 0.f;
#pragma unroll
    for (int q = 0; q < 16; ++q) {
      float4 xa = rowA[q];
      float4 xbv = rowB[q];
      aA = fmaf(w1r[4 * q + 0], xa.x, aA);
      aA = fmaf(w1r[4 * q + 1], xa.y, aA);
      aA = fmaf(w1r[4 * q + 2], xa.z, aA);
      aA = fmaf(w1r[4 * q + 3], xa.w, aA);
      aB = fmaf(w1r[4 * q + 0], xbv.x, aB);
      aB = fmaf(w1r[4 * q + 1], xbv.y, aB);
      aB = fmaf(w1r[4 * q + 2], xbv.z, aB);
      aB = fmaf(w1r[4 * q + 3], xbv.w, aB);
    }
    xls[k * FTW + lane] = fmaxf(fmaf(aA, s1l, b1l), 0.f);
    xls[(k + 1) * FTW + lane] = fmaxf(fmaf(aB, s1l, b1l), 0.f);
  }

  // ---- Layer 2: 64 -> 128 with fused max over the wave's 32 rows ----
  float w2a[64], w2b[64];
  {
    const float4* wpa = (const float4*)(w2 + lane * 64);
    const float4* wpb = (const float4*)(w2 + (64 + lane) * 64);
#pragma unroll
    for (int q = 0; q < 16; ++q) {
      float4 wv = wpa[q];
      w2a[4 * q + 0] = wv.x; w2a[4 * q + 1] = wv.y;
      w2a[4 * q + 2] = wv.z; w2a[4 * q + 3] = wv.w;
      float4 wu = wpb[q];
      w2b[4 * q + 0] = wu.x; w2b[4 * q + 1] = wu.y;
      w2b[4 * q + 2] = wu.z; w2b[4 * q + 3] = wu.w;
    }
  }
  const float s2a = s2[lane], b2a = b2[lane];
  const float s2b = s2[64 + lane], b2b = b2[64 + lane];
  float vmaxA = 0.f, vmaxB = 0.f;  // relu outputs are >= 0
  for (int kk = 0; kk < 32; ++kk) {
    const float4* row = (const float4*)(xls + (r0 + kk) * FTW);
    float aA = 0.f, aB = 0.f;
#pragma unroll
    for (int q = 0; q < 16; ++q) {
      float4 xa = row[q];
      aA = fmaf(w2a[4 * q + 0], xa.x, aA);
      aA = fmaf(w2a[4 * q + 1], xa.y, aA);
      aA = fmaf(w2a[4 * q + 2], xa.z, aA);
      aA = fmaf(w2a[4 * q + 3], xa.w, aA);
      aB = fmaf(w2b[4 * q + 0], xa.x, aB);
      aB = fmaf(w2b[4 * q + 1], xa.y, aB);
      aB = fmaf(w2b[4 * q + 2], xa.z, aB);
      aB = fmaf(w2b[4 * q + 3], xa.w, aB);
    }
    vmaxA = fmaxf(vmaxA, fmaxf(fmaf(aA, s2a, b2a), 0.f));
    vmaxB = fmaxf(vmaxB, fmaxf(fmaf(aB, s2b, b2b), 0.f));
  }
  red[w][lane] = vmaxA;
  red[w][64 + lane] = vmaxB;
  __syncthreads();
  float v = fmaxf(red[0][t128], red[1][t128]);
  out2[(size_t)((b << 7) + t128) * M_ + m] = v;
}

// ---------------------------------------------------------------------------
// K1: blocks 0-7 FPS[1,512) (or full range in fallback); blocks 8+ builders.
// ---------------------------------------------------------------------------
__global__ __launch_bounds__(256, 1) void fps_build_kernel(
    const float* __restrict__ xyz, const float* __restrict__ feat,
    const float* __restrict__ w0, float* __restrict__ w0pad, float* __restrict__ ft,
    float* __restrict__ nxyz, float* __restrict__ mindws, int* __restrict__ lastws,
    int i_begin, int i_end, int first, int builders) {
  __shared__ FpsShared sf;
  if (blockIdx.x >= 8) {
    if (!builders) return;
    if (blockIdx.x == 8) {
      for (int i = threadIdx.x; i < 64 * FTW; i += 256) {
        int o = i / FTW, c = i % FTW;
        w0pad[i] = (c < 67) ? w0[o * 67 + c] : 0.f;
      }
    }
    const int nb = gridDim.x - 8;
    const int total = B_ * N_ * FTW;
    for (int idx = (blockIdx.x - 8) * 256 + threadIdx.x; idx < total; idx += nb * 256) {
      int c = idx % FTW;
      int bn = idx / FTW;
      int n = bn & (N_ - 1);
      int b = bn >> 13;
      float v;
      if (c < 3) v = xyz[(b * 3 + c) * N_ + n];
      else if (c < 67) v = feat[(b * 64 + (c - 3)) * N_ + n];
      else v = 0.f;
      ft[idx] = v;
    }
    return;
  }
  const int b = blockIdx.x;
  fps_run(xyz + b * 3 * N_, nxyz + b * 3 * M_,
          mindws ? mindws + (b << 13) : nullptr, lastws ? lastws + b : nullptr,
          sf, i_begin, i_end, first != 0, threadIdx.x);
}

// ---------------------------------------------------------------------------
// K2: blocks 0-7 resume FPS[512,1024); blocks 8+ = worker pairs for
// m in [0,512) (2 independent 128-thread task groups per 256-thread block).
// The union makes worker blocks 128.3KB -> they can never colocate with an
// FPS block (1 block/CU), so workers cannot steal FPS issue slots.
// ---------------------------------------------------------------------------
__global__ __launch_bounds__(256, 1) void fps_work_kernel(
    const float* __restrict__ xyz, const float* __restrict__ ft,
    const float* __restrict__ w0pad, float* __restrict__ nxyz,
    float* __restrict__ mindws, int* __restrict__ lastws,
    const float* __restrict__ s0, const float* __restrict__ b0,
    const float* __restrict__ w1, const float* __restrict__ s1, const float* __restrict__ b1,
    const float* __restrict__ w2, const float* __restrict__ s2, const float* __restrict__ b2,
    float* __restrict__ out2) {
  __shared__ SMemU s;
  if (blockIdx.x < 8) {
    const int b = blockIdx.x;
    fps_run(xyz + b * 3 * N_, nxyz + b * 3 * M_, mindws + (b << 13), lastws + b,
            s.f, 512, 1024, false, threadIdx.x);
    return;
  }
  const int pair = blockIdx.x - 8;         // [0, 2048)
  const int tg = threadIdx.x >> 7;         // 0..1
  const int t128 = threadIdx.x & 127;
  const int task = pair * 2 + tg;          // [0, 4096)
  const int b = task >> 9;
  const int m = task & 511;                // m in [0, 512)
  work_task(b, m, t128, s.w.xls[tg], s.w.islot[tg], s.w.red[tg],
            xyz, ft, w0pad, nxyz, s0, b0, w1, s1, b1, w2, s2, b2, out2);
}

// ---------------------------------------------------------------------------
// K3: lean worker kernel for m in [m_off, m_off+512). One task per 128-thread
// block; 18.7KB LDS -> R14-level occupancy.
// ---------------------------------------------------------------------------
__global__ __launch_bounds__(128, 2) void work_kernel(
    const float* __restrict__ xyz, const float* __restrict__ ft,
    const float* __restrict__ w0pad, const float* __restrict__ nxyz,
    const float* __restrict__ s0, const float* __restrict__ b0,
    const float* __restrict__ w1, const float* __restrict__ s1, const float* __restrict__ b1,
    const float* __restrict__ w2, const float* __restrict__ s2, const float* __restrict__ b2,
    float* __restrict__ out2, int m_off) {
  __shared__ float xls[64 * FTW];
  __shared__ int islot[64];
  __shared__ float red[2][128];
  const int task = blockIdx.x;             // [0, 4096)
  const int b = task >> 9;
  const int m = m_off + (task & 511);
  work_task(b, m, threadIdx.x, xls, islot, red,
            xyz, ft, w0pad, nxyz, s0, b0, w1, s1, b1, w2, s2, b2, out2);
}

// ---------------------------------------------------------------------------
// Fallback path kernels (no-ws): standalone ballq + lane=neighbor MLP.
// ---------------------------------------------------------------------------
__global__ __launch_bounds__(256) void ballq_kernel(const float* __restrict__ xyz,
                                                    const float* __restrict__ nxyz,
                                                    int* __restrict__ nidx) {
  const int lane = threadIdx.x & 63;
  const int g = blockIdx.x * 4 + (threadIdx.x >> 6);
  const int b = g >> 10;
  const int m = g & (M_ - 1);
  const float* xb = xyz + b * 3 * N_;
  const float cx = nxyz[b * 3 * M_ + m];
  const float cy = nxyz[b * 3 * M_ + M_ + m];
  const float cz = nxyz[b * 3 * M_ + 2 * M_ + m];
  const float nc = __fadd_rn(__fadd_rn(__fmul_rn(cx, cx), __fmul_rn(cy, cy)), __fmul_rn(cz, cz));
  int cnt = 0;
  int first = 0;
  int* slot = nidx + (g << 6);
  for (int basei = 0; basei < N_ && cnt < K_; basei += 64) {
    const int n = basei + lane;
    float p_x = xb[n], p_y = xb[N_ + n], p_z = xb[2 * N_ + n];
    float pn = __fadd_rn(__fadd_rn(__fmul_rn(p_x, p_x), __fmul_rn(p_y, p_y)), __fmul_rn(p_z, p_z));
    float dt = __fadd_rn(__fadd_rn(__fmul_rn(cx, p_x), __fmul_rn(cy, p_y)), __fmul_rn(cz, p_z));
    float d2 = __fsub_rn(__fadd_rn(nc, pn), __fmul_rn(2.f, dt));
    bool inr = d2 < 0.04f;
    unsigned long long mk = __ballot(inr);
    if (cnt == 0 && mk != 0ull) first = basei + (__ffsll((long long)mk) - 1);
    int pos = cnt + (int)__popcll(mk & ((1ull << lane) - 1ull));
    if (inr && pos < K_) slot[pos] = n;
    cnt += (int)__popcll(mk);
  }
  if (cnt > K_) cnt = K_;
  if (lane >= cnt) slot[lane] = first;
}

__global__ __launch_bounds__(64, 4) void mlp_kernel_fb(
    const float* __restrict__ xyz, const float* __restrict__ feat,
    const int* __restrict__ nidx, const float* __restrict__ nxyz,
    const float* __restrict__ w0, const float* __restrict__ s0, const float* __restrict__ b0,
    const float* __restrict__ w1, const float* __restrict__ s1, const float* __restrict__ b1,
    const float* __restrict__ w2, const float* __restrict__ s2, const float* __restrict__ b2,
    float* __restrict__ out2) {
  __shared__ float ylds[64 * 33];
  const int g = blockIdx.x;
  const int b = g >> 10;
  const int m = g & (M_ - 1);
  const int lane = threadIdx.x;
  const int n = nidx[(g << 6) + lane];
  const float cx = nxyz[b * 3 * M_ + m];
  const float cy = nxyz[b * 3 * M_ + M_ + m];
  const float cz = nxyz[b * 3 * M_ + 2 * M_ + m];

  float x0[67];
  const float* xb = xyz + b * 3 * N_;
  x0[0] = xb[n] - cx; x0[1] = xb[N_ + n] - cy; x0[2] = xb[2 * N_ + n] - cz;
#pragma unroll
  for (int c = 0; c < 64; ++c) x0[3 + c] = feat[((b << 6) + c) * N_ + n];

  float x1[64];
#pragma unroll
  for (int h = 0; h < 2; ++h) {
#pragma unroll 2
    for (int oo = 0; oo < 32; oo += 4) {
      const int o = h * 32 + oo;
      const float* wr = w0 + o * 67;
      float a0 = 0.f, a1 = 0.f, a2 = 0.f, a3 = 0.f;
#pragma unroll
      for (int ci = 0; ci < 67; ++ci) {
        float xvv = x0[ci];
        a0 = fmaf(wr[ci], xvv, a0);
        a1 = fmaf(wr[67 + ci], xvv, a1);
        a2 = fmaf(wr[134 + ci], xvv, a2);
        a3 = fmaf(wr[201 + ci], xvv, a3);
      }
      ylds[lane * 33 + oo + 0] = fmaxf(fmaf(a0, s0[o + 0], b0[o + 0]), 0.f);
      ylds[lane * 33 + oo + 1] = fmaxf(fmaf(a1, s0[o + 1], b0[o + 1]), 0.f);
      ylds[lane * 33 + oo + 2] = fmaxf(fmaf(a2, s0[o + 2], b0[o + 2]), 0.f);
      ylds[lane * 33 + oo + 3] = fmaxf(fmaf(a3, s0[o + 3], b0[o + 3]), 0.f);
    }
#pragma unroll
    for (int c = 0; c < 32; ++c) x1[h * 32 + c] = ylds[lane * 33 + c];
  }

  float x2[64];
#pragma unroll
  for (int h = 0; h < 2; ++h) {
#pragma unroll 2
    for (int oo = 0; oo < 32; oo += 4) {
      const int o = h * 32 + oo;
      const float* wr = w1 + o * 64;
      float a0 = 0.f, a1 = 0.f, a2 = 0.f, a3 = 0.f;
#pragma unroll
      for (int ci = 0; ci < 64; ++ci) {
        float xvv = x1[ci];
        a0 = fmaf(wr[ci], xvv, a0);
        a1 = fmaf(wr[64 + ci], xvv, a1);
        a2 = fmaf(wr[128 + ci], xvv, a2);
        a3 = fmaf(wr[192 + ci], xvv, a3);
      }
      ylds[lane * 33 + oo + 0] = fmaxf(fmaf(a0, s1[o + 0], b1[o + 0]), 0.f);
      ylds[lane * 33 + oo + 1] = fmaxf(fmaf(a1, s1[o + 1], b1[o + 1]), 0.f);
      ylds[lane * 33 + oo + 2] = fmaxf(fmaf(a2, s1[o + 2], b1[o + 2]), 0.f);
      ylds[lane * 33 + oo + 3] = fmaxf(fmaf(a3, s1[o + 3], b1[o + 3]), 0.f);
    }
#pragma unroll
    for (int c = 0; c < 32; ++c) x2[h * 32 + c] = ylds[lane * 33 + c];
  }

  float* outbm = out2 + (size_t)(b * 128) * M_ + m;
#pragma unroll 2
  for (int o = 0; o < 128; o += 4) {
    const float* wr = w2 + o * 64;
    float a0 = 0.f, a1 = 0.f, a2 = 0.f, a3 = 0.f;
#pragma unroll
    for (int ci = 0; ci < 64; ++ci) {
      float xvv = x2[ci];
      a0 = fmaf(wr[ci], xvv, a0);
      a1 = fmaf(wr[64 + ci], xvv, a1);
      a2 = fmaf(wr[128 + ci], xvv, a2);
      a3 = fmaf(wr[192 + ci], xvv, a3);
    }
    float v0 = fmaxf(fmaf(a0, s2[o + 0], b2[o + 0]), 0.f);
    float v1 = fmaxf(fmaf(a1, s2[o + 1], b2[o + 1]), 0.f);
    float v2 = fmaxf(fmaf(a2, s2[o + 2], b2[o + 2]), 0.f);
    float v3 = fmaxf(fmaf(a3, s2[o + 3], b2[o + 3]), 0.f);
    v0 = wave_fmax63(v0);
    v1 = wave_fmax63(v1);
    v2 = wave_fmax63(v2);
    v3 = wave_fmax63(v3);
    float g0 = __int_as_float(__builtin_amdgcn_readlane(__float_as_int(v0), 63));
    float g1 = __int_as_float(__builtin_amdgcn_readlane(__float_as_int(v1), 63));
    float g2 = __int_as_float(__builtin_amdgcn_readlane(__float_as_int(v2), 63));
    float g3 = __int_as_float(__builtin_amdgcn_readlane(__float_as_int(v3), 63));
    if (lane == ((o + 0) & 63)) outbm[(o + 0) * M_] = g0;
    if (lane == ((o + 1) & 63)) outbm[(o + 1) * M_] = g1;
    if (lane == ((o + 2) & 63)) outbm[(o + 2) * M_] = g2;
    if (lane == ((o + 3) & 63)) outbm[(o + 3) * M_] = g3;
  }
}

// ---------------------------------------------------------------------------
extern "C" void kernel_launch(void* const* d_in, const int* in_sizes, int n_in,
                              void* d_out, int out_size, void* d_ws, size_t ws_size,
                              hipStream_t stream) {
  const float* xyz = (const float*)d_in[0];
  const float* feat = (const float*)d_in[1];
  const float* w0 = (const float*)d_in[2];
  const float* s0 = (const float*)d_in[3];
  const float* b0 = (const float*)d_in[4];
  const float* w1 = (const float*)d_in[5];
  const float* s1 = (const float*)d_in[6];
  const float* b1 = (const float*)d_in[7];
  const float* w2 = (const float*)d_in[8];
  const float* s2 = (const float*)d_in[9];
  const float* b2 = (const float*)d_in[10];

  float* nxyz = (float*)d_out;                    // [8,3,1024]
  float* out2 = (float*)d_out + B_ * 3 * M_;      // [8,128,1024]

  // ws layout: w0pad [17408] | mind [8*8192*4=262144] | last [32] | ft [~17.8MB]
  const size_t w0p_off = 0;
  const size_t mind_off = 17408;
  const size_t last_off = mind_off + (size_t)B_ * 8192 * sizeof(float);
  const size_t ft_off = last_off + 32;
  const size_t ft_bytes = (size_t)B_ * N_ * FTW * sizeof(float);
  float* w0pad = (float*)((char*)d_ws + w0p_off);
  float* mindws = (float*)((char*)d_ws + mind_off);
  int* lastws = (int*)((char*)d_ws + last_off);
  float* ft = (float*)((char*)d_ws + ft_off);
  const bool use_ft = ws_size >= ft_off + ft_bytes;

  if (use_ft) {
    // K1: FPS[1,512) + builders
    hipLaunchKernelGGL(fps_build_kernel, dim3(64), dim3(256), 0, stream,
                       xyz, feat, w0, w0pad, ft, nxyz, mindws, lastws, 1, 512, 1, 1);
    // K2: FPS[512,1024)  ||  workers m in [0,512)
    hipLaunchKernelGGL(fps_work_kernel, dim3(8 + 2048), dim3(256), 0, stream,
                       xyz, ft, w0pad, nxyz, mindws, lastws,
                       s0, b0, w1, s1, b1, w2, s2, b2, out2);
    // K3: workers m in [512,1024)
    hipLaunchKernelGGL(work_kernel, dim3(4096), dim3(128), 0, stream,
                       xyz, ft, w0pad, nxyz, s0, b0, w1, s1, b1, w2, s2, b2, out2, 512);
  } else {
    // Fallback: monolithic FPS + standalone ballq + lane=neighbor MLP.
    int* nidx = (int*)d_ws;  // 2 MB
    hipLaunchKernelGGL(fps_build_kernel, dim3(8), dim3(256), 0, stream,
                       xyz, feat, w0, nullptr, nullptr, nxyz, nullptr, nullptr, 1, 1024, 1, 0);
    hipLaunchKernelGGL(ballq_kernel, dim3(B_ * M_ / 4), dim3(256), 0, stream, xyz, nxyz, nidx);
    hipLaunchKernelGGL(mlp_kernel_fb, dim3(B_ * M_), dim3(64), 0, stream,
                       xyz, feat, nidx, nxyz, w0, s0, b0, w1, s1, b1, w2, s2, b2, out2);
  }
}

// Round 16
// 1233.779 us; speedup vs baseline: 1.8593x; 1.8593x over previous
//
#include <hip/hip_runtime.h>

// PointNet++ SA module: FPS -> ball query -> group -> SharedMLP(3) -> maxpool
// B=8, N=8192, C_IN=64, M=1024, K=64, RADIUS=0.2, MLP=[64,64,128]

#define B_ 8
#define N_ 8192
#define M_ 1024
#define K_ 64
#define FTW 68  // 3 xyz + 64 feat + 1 pad (row = 272B, 16B aligned)

// ---------------------------------------------------------------------------
// u64-key lexicographic merge via DPP (VALU pipe, no LDS).
// key = (f32bits(val) << 32) | ~idx ; distances >= 0 so f32 bits order as u32.
// max(key) == (val desc, idx asc) — associative, any mixing schedule valid.
// ---------------------------------------------------------------------------
template <int CTRL>
__device__ __forceinline__ unsigned long long dpp_key(unsigned long long k) {
  int lo = __builtin_amdgcn_update_dpp(0, (int)(unsigned int)k, CTRL, 0xF, 0xF, true);
  int hi = __builtin_amdgcn_update_dpp(0, (int)(unsigned int)(k >> 32), CTRL, 0xF, 0xF, true);
  unsigned long long o = ((unsigned long long)(unsigned int)hi << 32) | (unsigned int)lo;
  return o > k ? o : k;
}

// 6-level DPP max (pure VALU), used by the fallback mlp path.
template <int CTRL>
__device__ __forceinline__ float dpp_fmax(float v) {
  int o = __builtin_amdgcn_update_dpp(0, __float_as_int(v), CTRL, 0xF, 0xF, true);
  return fmaxf(v, __int_as_float(o));
}
__device__ __forceinline__ float wave_fmax63(float v) {
  v = dpp_fmax<0xB1>(v);
  v = dpp_fmax<0x4E>(v);
  v = dpp_fmax<0x141>(v);
  v = dpp_fmax<0x140>(v);
  v = dpp_fmax<0x142>(v);
  v = dpp_fmax<0x143>(v);
  return v;
}

// ---------------------------------------------------------------------------
// Kernel 1 (fused): blocks 0..7 = exact FPS (one CU per batch);
//                   blocks 8..  = build ft table + padded w0 (stride 68).
// FPS: 256 threads (4 waves, 1/SIMD) x 32 points — R4/R8 schedule, measured
// best (890us) of all 7 schedule variants tried (R2..R10,R15). ONE barrier
// per iteration, parity double-buffered candidates; index carried in the u64
// key so the post-barrier combine is per-thread self-contained.
// Arithmetic identical to reference: unfused f32 sub/mul/add in x,y,z order;
// argmax tie-break = first occurrence (lexicographic val desc, idx asc).
// ---------------------------------------------------------------------------
__global__ __launch_bounds__(256, 1) void fps_ft_kernel(const float* __restrict__ xyz,
                                                        const float* __restrict__ feat,
                                                        const float* __restrict__ w0,
                                                        float* __restrict__ w0pad,
                                                        float* __restrict__ ft,
                                                        float* __restrict__ nxyz) {
#pragma clang fp contract(off)
  if (blockIdx.x >= 8) {
    // ---- builder path (no LDS use, no barriers) ----
    if (blockIdx.x == 8) {
      // padded w0: [64][68], cols 67 = 0 (16B-aligned rows for float4 loads)
      for (int i = threadIdx.x; i < 64 * FTW; i += 256) {
        int o = i / FTW, c = i % FTW;
        w0pad[i] = (c < 67) ? w0[o * 67 + c] : 0.f;
      }
    }
    const int nb = gridDim.x - 8;
    const int total = B_ * N_ * FTW;
    for (int idx = (blockIdx.x - 8) * 256 + threadIdx.x; idx < total; idx += nb * 256) {
      int c = idx % FTW;
      int bn = idx / FTW;
      int n = bn & (N_ - 1);
      int b = bn >> 13;
      float v;
      if (c < 3) v = xyz[(b * 3 + c) * N_ + n];
      else if (c < 67) v = feat[(b * 64 + (c - 3)) * N_ + n];
      else v = 0.f;
      ft[idx] = v;
    }
    return;
  }

  // ---- FPS path ----
  __shared__ float4 pts4[N_];                    // 128 KB point table (w unused)
  __shared__ unsigned long long cand[2][16];     // parity-buffered row-winner keys
  __shared__ int scidx[M_];
  const int b = blockIdx.x;
  const int t = threadIdx.x;
  const int lane = t & 63;
  const int wid = t >> 6;  // 0..3
  const float* xb = xyz + b * 3 * N_;

  for (int n = t; n < N_; n += 256) {
    pts4[n] = make_float4(xb[n], xb[N_ + n], xb[2 * N_ + n], 0.f);
  }

  const int base = t * 32;
  float px[32], py[32], pz[32], mind[32];
#pragma unroll
  for (int j = 0; j < 32; ++j) {
    px[j] = xb[base + j];
    py[j] = xb[N_ + base + j];
    pz[j] = xb[2 * N_ + base + j];
    mind[j] = 1e10f;
  }
  float xl = xb[0], yl = xb[N_], zl = xb[2 * N_];
  if (t == 0) scidx[0] = 0;
  __syncthreads();

  for (int i = 1; i < M_; ++i) {
    float bestv = -1.f;
    int bl = 0;  // local index 0..31 (inline-const cndmask)
#pragma unroll
    for (int j = 0; j < 32; ++j) {
      float dx = __fsub_rn(px[j], xl);
      float dy = __fsub_rn(py[j], yl);
      float dz = __fsub_rn(pz[j], zl);
      float d = __fadd_rn(__fadd_rn(__fmul_rn(dx, dx), __fmul_rn(dy, dy)), __fmul_rn(dz, dz));
      float md = fminf(mind[j], d);
      mind[j] = md;
      if (md > bestv) { bestv = md; bl = j; }  // ascending j -> first max kept
    }
    unsigned long long key =
        ((unsigned long long)__float_as_uint(bestv) << 32) | (unsigned int)(~(base + bl));
    key = dpp_key<0xB1>(key);   // quad_perm [1,0,3,2]
    key = dpp_key<0x4E>(key);   // quad_perm [2,3,0,1]
    key = dpp_key<0x141>(key);  // row_half_mirror
    key = dpp_key<0x140>(key);  // row_mirror -> 16-lane-row winner
    if ((lane & 15) == 0) cand[i & 1][wid * 4 + (lane >> 4)] = key;
    __syncthreads();
    unsigned long long gk = cand[i & 1][lane & 15];
    gk = dpp_key<0xB1>(gk);
    gk = dpp_key<0x4E>(gk);
    gk = dpp_key<0x141>(gk);
    gk = dpp_key<0x140>(gk);
    const int gi = (int)(~(unsigned int)gk);
    if (t == 0) scidx[i] = gi;
    float4 cc = pts4[gi];  // broadcast ds_read_b128, conflict-free
    xl = cc.x; yl = cc.y; zl = cc.z;
    // no second barrier: next iteration's leader writes go to the other parity
  }
  __syncthreads();
  for (int q = t; q < M_; q += 256) {
    int ci = scidx[q];
    float4 c = pts4[ci];
    nxyz[b * 3 * M_ + q] = c.x;
    nxyz[b * 3 * M_ + M_ + q] = c.y;
    nxyz[b * 3 * M_ + 2 * M_ + q] = c.z;
  }
}

// ---------------------------------------------------------------------------
// Kernel 2: ball query — one wave per centroid, ordered first-K within radius.
// STANDALONE (R11/R15 both measured fusing it into the worker as a loss: the
// early-exit chunk loop serializes VMEM latency; standalone runs at full
// dispatch parallelism). Expanded-form distance exactly as reference.
// ---------------------------------------------------------------------------
__global__ __launch_bounds__(256) void ballq_kernel(const float* __restrict__ xyz,
                                                    const float* __restrict__ nxyz,
                                                    int* __restrict__ nidx) {
  const int lane = threadIdx.x & 63;
  const int g = blockIdx.x * 4 + (threadIdx.x >> 6);  // 0..8191 centroid id
  const int b = g >> 10;
  const int m = g & (M_ - 1);
  const float* xb = xyz + b * 3 * N_;
  const float cx = nxyz[b * 3 * M_ + m];
  const float cy = nxyz[b * 3 * M_ + M_ + m];
  const float cz = nxyz[b * 3 * M_ + 2 * M_ + m];
  const float nc = __fadd_rn(__fadd_rn(__fmul_rn(cx, cx), __fmul_rn(cy, cy)), __fmul_rn(cz, cz));
  int cnt = 0;
  int first = 0;
  int* slot = nidx + (g << 6);
  for (int basei = 0; basei < N_ && cnt < K_; basei += 64) {
    const int n = basei + lane;
    float p_x = xb[n], p_y = xb[N_ + n], p_z = xb[2 * N_ + n];
    float pn = __fadd_rn(__fadd_rn(__fmul_rn(p_x, p_x), __fmul_rn(p_y, p_y)), __fmul_rn(p_z, p_z));
    float dt = __fadd_rn(__fadd_rn(__fmul_rn(cx, p_x), __fmul_rn(cy, p_y)), __fmul_rn(cz, p_z));
    float d2 = __fsub_rn(__fadd_rn(nc, pn), __fmul_rn(2.f, dt));
    bool inr = d2 < 0.04f;
    unsigned long long mk = __ballot(inr);
    if (cnt == 0 && mk != 0ull) first = basei + (__ffsll((long long)mk) - 1);
    int pos = cnt + (int)__popcll(mk & ((1ull << lane) - 1ull));
    if (inr && pos < K_) slot[pos] = n;
    cnt += (int)__popcll(mk);
  }
  if (cnt > K_) cnt = K_;
  if (lane >= cnt) slot[lane] = first;  // pad with first hit (0 if none)
}

// ---------------------------------------------------------------------------
// Kernel 3 (primary): TRANSPOSED fused group+MLP+maxpool, two waves per task.
// Block = 128 threads; lane = OUTPUT CHANNEL.
// Layers 0/1: wave w owns rows [32w,32w+32) (row k depends only on row k ->
//   waves independent). Weights per-lane in VGPRs (vector loads, once/layer);
//   activations in a 64x68 LDS buffer consumed as broadcast ds_read_b128,
//   overwritten in place (in-order DS within the owning wave; rows disjoint).
// R16 layer 2 (occupancy fix vs R14): wave w owns CHANNEL half [64w,64w+64)
//   over ALL 64 rows -> only 64 weight VGPRs (R14's 128-reg w2a+w2b was the
//   VGPR peak capping residency at ~2 blocks/CU; R15 counters: occ 12%,
//   VALUBusy 13% = latency-bound). One __syncthreads() after layer 1 makes
//   the other wave's rows visible; maxpool folds into running fmaxf (rows
//   k,k+1 as 2 independent chains); direct out2 store, no LDS combine.
// FMA count & order per output identical to reference (ci ascending; padded
// 68th term is 0*0 -> exact; max is exact in any order). absmax stays 0.
// ---------------------------------------------------------------------------
__global__ __launch_bounds__(128, 4) void mlp_t_kernel(
    const float* __restrict__ ft, const float* __restrict__ w0pad,
    const int* __restrict__ nidx, const float* __restrict__ nxyz,
    const float* __restrict__ s0, const float* __restrict__ b0,
    const float* __restrict__ w1, const float* __restrict__ s1, const float* __restrict__ b1,
    const float* __restrict__ w2, const float* __restrict__ s2, const float* __restrict__ b2,
    float* __restrict__ out2) {
  __shared__ float xls[64 * FTW];  // 17408 B activation buffer, reused per layer
  const int g = blockIdx.x;
  const int b = g >> 10;
  const int m = g & (M_ - 1);
  const int t = threadIdx.x;
  const int lane = t & 63;
  const int wid = t >> 6;  // 0..1
  const int r0 = wid * 32;

  const float cx = nxyz[b * 3 * M_ + m];
  const float cy = nxyz[b * 3 * M_ + M_ + m];
  const float cz = nxyz[b * 3 * M_ + 2 * M_ + m];

  // ---- stage: thread t copies half of row (t>>1) to LDS (recentered xyz) ----
  {
    const int row = t >> 1;
    const int half = t & 1;
    const int nk = nidx[(g << 6) + row];
    const float4* src = (const float4*)(ft + (size_t)((b << 13) + nk) * FTW);
    float4* dst = (float4*)(xls + row * FTW);
    if (half == 0) {
      float4 v0 = src[0];
      v0.x -= cx; v0.y -= cy; v0.z -= cz;
      dst[0] = v0;
#pragma unroll
      for (int q = 1; q < 8; ++q) dst[q] = src[q];
    } else {
#pragma unroll
      for (int q = 8; q < 17; ++q) dst[q] = src[q];
    }
  }
  __syncthreads();

  // ---- Layer 0: 67(+pad) -> 64 ; weights in 68 VGPRs ----
  float w0r[FTW];
  {
    const float4* wp = (const float4*)(w0pad + lane * FTW);
#pragma unroll
    for (int q = 0; q < 17; ++q) {
      float4 wv = wp[q];
      w0r[4 * q + 0] = wv.x; w0r[4 * q + 1] = wv.y;
      w0r[4 * q + 2] = wv.z; w0r[4 * q + 3] = wv.w;
    }
  }
  const float s0l = s0[lane], b0l = b0[lane];
  for (int kk = 0; kk < 32; kk += 2) {
    const int k = r0 + kk;
    const float4* rowA = (const float4*)(xls + k * FTW);
    const float4* rowB = (const float4*)(xls + (k + 1) * FTW);
    float aA = 0.f, aB = 0.f;
#pragma unroll
    for (int q = 0; q < 17; ++q) {
      float4 xa = rowA[q];
      float4 xbv = rowB[q];
      aA = fmaf(w0r[4 * q + 0], xa.x, aA);
      aA = fmaf(w0r[4 * q + 1], xa.y, aA);
      aA = fmaf(w0r[4 * q + 2], xa.z, aA);
      aA = fmaf(w0r[4 * q + 3], xa.w, aA);
      aB = fmaf(w0r[4 * q + 0], xbv.x, aB);
      aB = fmaf(w0r[4 * q + 1], xbv.y, aB);
      aB = fmaf(w0r[4 * q + 2], xbv.z, aB);
      aB = fmaf(w0r[4 * q + 3], xbv.w, aB);
    }
    xls[k * FTW + lane] = fmaxf(fmaf(aA, s0l, b0l), 0.f);
    xls[(k + 1) * FTW + lane] = fmaxf(fmaf(aB, s0l, b0l), 0.f);
  }

  // ---- Layer 1: 64 -> 64 ; weights in 64 VGPRs ----
  float w1r[64];
  {
    const float4* wp = (const float4*)(w1 + lane * 64);
#pragma unroll
    for (int q = 0; q < 16; ++q) {
      float4 wv = wp[q];
      w1r[4 * q + 0] = wv.x; w1r[4 * q + 1] = wv.y;
      w1r[4 * q + 2] = wv.z; w1r[4 * q + 3] = wv.w;
    }
  }
  const float s1l = s1[lane], b1l = b1[lane];
  for (int kk = 0; kk < 32; kk += 2) {
    const int k = r0 + kk;
    const float4* rowA = (const float4*)(xls + k * FTW);
    const float4* rowB = (const float4*)(xls + (k + 1) * FTW);
    float aA = 0.f, aB = 0.f;
#pragma unroll
    for (int q = 0; q < 16; ++q) {
      float4 xa = rowA[q];
      float4 xbv = rowB[q];
      aA = fmaf(w1r[4 * q + 0], xa.x, aA);
      aA = fmaf(w1r[4 * q + 1], xa.y, aA);
      aA = fmaf(w1r[4 * q + 2], xa.z, aA);
      aA = fmaf(w1r[4 * q + 3], xa.w, aA);
      aB = fmaf(w1r[4 * q + 0], xbv.x, aB);
      aB = fmaf(w1r[4 * q + 1], xbv.y, aB);
      aB = fmaf(w1r[4 * q + 2], xbv.z, aB);
      aB = fmaf(w1r[4 * q + 3], xbv.w, aB);
    }
    xls[k * FTW + lane] = fmaxf(fmaf(aA, s1l, b1l), 0.f);
    xls[(k + 1) * FTW + lane] = fmaxf(fmaf(aB, s1l, b1l), 0.f);
  }
  __syncthreads();  // other wave's 32 rows of layer-1 output become visible

  // ---- Layer 2: wave's channel ch = wid*64+lane over ALL 64 rows ----
  const int ch = (wid << 6) + lane;
  float w2r[64];
  {
    const float4* wp = (const float4*)(w2 + ch * 64);
#pragma unroll
    for (int q = 0; q < 16; ++q) {
      float4 wv = wp[q];
      w2r[4 * q + 0] = wv.x; w2r[4 * q + 1] = wv.y;
      w2r[4 * q + 2] = wv.z; w2r[4 * q + 3] = wv.w;
    }
  }
  const float s2c = s2[ch], b2c = b2[ch];
  float vmax = 0.f;  // relu outputs are >= 0
  for (int k = 0; k < 64; k += 2) {
    const float4* rowA = (const float4*)(xls + k * FTW);
    const float4* rowB = (const float4*)(xls + (k + 1) * FTW);
    float aA = 0.f, aB = 0.f;
#pragma unroll
    for (int q = 0; q < 16; ++q) {
      float4 xa = rowA[q];
      float4 xbv = rowB[q];
      aA = fmaf(w2r[4 * q + 0], xa.x, aA);
      aA = fmaf(w2r[4 * q + 1], xa.y, aA);
      aA = fmaf(w2r[4 * q + 2], xa.z, aA);
      aA = fmaf(w2r[4 * q + 3], xa.w, aA);
      aB = fmaf(w2r[4 * q + 0], xbv.x, aB);
      aB = fmaf(w2r[4 * q + 1], xbv.y, aB);
      aB = fmaf(w2r[4 * q + 2], xbv.z, aB);
      aB = fmaf(w2r[4 * q + 3], xbv.w, aB);
    }
    vmax = fmaxf(vmax, fmaxf(fmaf(aA, s2c, b2c), 0.f));
    vmax = fmaxf(vmax, fmaxf(fmaf(aB, s2c, b2c), 0.f));
  }
  out2[(size_t)((b << 7) + ch) * M_ + m] = vmax;
}

// ---------------------------------------------------------------------------
// Kernel 3 (fallback, no-ws path): R12 mlp (lane = neighbor, scalar weights).
// ---------------------------------------------------------------------------
__global__ __launch_bounds__(64, 4) void mlp_kernel_fb(
    const float* __restrict__ xyz, const float* __restrict__ feat,
    const int* __restrict__ nidx, const float* __restrict__ nxyz,
    const float* __restrict__ w0, const float* __restrict__ s0, const float* __restrict__ b0,
    const float* __restrict__ w1, const float* __restrict__ s1, const float* __restrict__ b1,
    const float* __restrict__ w2, const float* __restrict__ s2, const float* __restrict__ b2,
    float* __restrict__ out2) {
  __shared__ float ylds[64 * 33];
  const int g = blockIdx.x;
  const int b = g >> 10;
  const int m = g & (M_ - 1);
  const int lane = threadIdx.x;
  const int n = nidx[(g << 6) + lane];
  const float cx = nxyz[b * 3 * M_ + m];
  const float cy = nxyz[b * 3 * M_ + M_ + m];
  const float cz = nxyz[b * 3 * M_ + 2 * M_ + m];

  float x0[67];
  const float* xb = xyz + b * 3 * N_;
  x0[0] = xb[n] - cx; x0[1] = xb[N_ + n] - cy; x0[2] = xb[2 * N_ + n] - cz;
#pragma unroll
  for (int c = 0; c < 64; ++c) x0[3 + c] = feat[((b << 6) + c) * N_ + n];

  float x1[64];
#pragma unroll
  for (int h = 0; h < 2; ++h) {
#pragma unroll 2
    for (int oo = 0; oo < 32; oo += 4) {
      const int o = h * 32 + oo;
      const float* wr = w0 + o * 67;
      float a0 = 0.f, a1 = 0.f, a2 = 0.f, a3 = 0.f;
#pragma unroll
      for (int ci = 0; ci < 67; ++ci) {
        float xvv = x0[ci];
        a0 = fmaf(wr[ci], xvv, a0);
        a1 = fmaf(wr[67 + ci], xvv, a1);
        a2 = fmaf(wr[134 + ci], xvv, a2);
        a3 = fmaf(wr[201 + ci], xvv, a3);
      }
      ylds[lane * 33 + oo + 0] = fmaxf(fmaf(a0, s0[o + 0], b0[o + 0]), 0.f);
      ylds[lane * 33 + oo + 1] = fmaxf(fmaf(a1, s0[o + 1], b0[o + 1]), 0.f);
      ylds[lane * 33 + oo + 2] = fmaxf(fmaf(a2, s0[o + 2], b0[o + 2]), 0.f);
      ylds[lane * 33 + oo + 3] = fmaxf(fmaf(a3, s0[o + 3], b0[o + 3]), 0.f);
    }
#pragma unroll
    for (int c = 0; c < 32; ++c) x1[h * 32 + c] = ylds[lane * 33 + c];
  }

  float x2[64];
#pragma unroll
  for (int h = 0; h < 2; ++h) {
#pragma unroll 2
    for (int oo = 0; oo < 32; oo += 4) {
      const int o = h * 32 + oo;
      const float* wr = w1 + o * 64;
      float a0 = 0.f, a1 = 0.f, a2 = 0.f, a3 = 0.f;
#pragma unroll
      for (int ci = 0; ci < 64; ++ci) {
        float xvv = x1[ci];
        a0 = fmaf(wr[ci], xvv, a0);
        a1 = fmaf(wr[64 + ci], xvv, a1);
        a2 = fmaf(wr[128 + ci], xvv, a2);
        a3 = fmaf(wr[192 + ci], xvv, a3);
      }
      ylds[lane * 33 + oo + 0] = fmaxf(fmaf(a0, s1[o + 0], b1[o + 0]), 0.f);
      ylds[lane * 33 + oo + 1] = fmaxf(fmaf(a1, s1[o + 1], b1[o + 1]), 0.f);
      ylds[lane * 33 + oo + 2] = fmaxf(fmaf(a2, s1[o + 2], b1[o + 2]), 0.f);
      ylds[lane * 33 + oo + 3] = fmaxf(fmaf(a3, s1[o + 3], b1[o + 3]), 0.f);
    }
#pragma unroll
    for (int c = 0; c < 32; ++c) x2[h * 32 + c] = ylds[lane * 33 + c];
  }

  float* outbm = out2 + (size_t)(b * 128) * M_ + m;
#pragma unroll 2
  for (int o = 0; o < 128; o += 4) {
    const float* wr = w2 + o * 64;
    float a0 = 0.f, a1 = 0.f, a2 = 0.f, a3 = 0.f;
#pragma unroll
    for (int ci = 0; ci < 64; ++ci) {
      float xvv = x2[ci];
      a0 = fmaf(wr[ci], xvv, a0);
      a1 = fmaf(wr[64 + ci], xvv, a1);
      a2 = fmaf(wr[128 + ci], xvv, a2);
      a3 = fmaf(wr[192 + ci], xvv, a3);
    }
    float v0 = fmaxf(fmaf(a0, s2[o + 0], b2[o + 0]), 0.f);
    float v1 = fmaxf(fmaf(a1, s2[o + 1], b2[o + 1]), 0.f);
    float v2 = fmaxf(fmaf(a2, s2[o + 2], b2[o + 2]), 0.f);
    float v3 = fmaxf(fmaf(a3, s2[o + 3], b2[o + 3]), 0.f);
    v0 = wave_fmax63(v0);
    v1 = wave_fmax63(v1);
    v2 = wave_fmax63(v2);
    v3 = wave_fmax63(v3);
    float g0 = __int_as_float(__builtin_amdgcn_readlane(__float_as_int(v0), 63));
    float g1 = __int_as_float(__builtin_amdgcn_readlane(__float_as_int(v1), 63));
    float g2 = __int_as_float(__builtin_amdgcn_readlane(__float_as_int(v2), 63));
    float g3 = __int_as_float(__builtin_amdgcn_readlane(__float_as_int(v3), 63));
    if (lane == ((o + 0) & 63)) outbm[(o + 0) * M_] = g0;
    if (lane == ((o + 1) & 63)) outbm[(o + 1) * M_] = g1;
    if (lane == ((o + 2) & 63)) outbm[(o + 2) * M_] = g2;
    if (lane == ((o + 3) & 63)) outbm[(o + 3) * M_] = g3;
  }
}

// ---------------------------------------------------------------------------
extern "C" void kernel_launch(void* const* d_in, const int* in_sizes, int n_in,
                              void* d_out, int out_size, void* d_ws, size_t ws_size,
                              hipStream_t stream) {
  const float* xyz = (const float*)d_in[0];
  const float* feat = (const float*)d_in[1];
  const float* w0 = (const float*)d_in[2];
  const float* s0 = (const float*)d_in[3];
  const float* b0 = (const float*)d_in[4];
  const float* w1 = (const float*)d_in[5];
  const float* s1 = (const float*)d_in[6];
  const float* b1 = (const float*)d_in[7];
  const float* w2 = (const float*)d_in[8];
  const float* s2 = (const float*)d_in[9];
  const float* b2 = (const float*)d_in[10];

  float* nxyz = (float*)d_out;                    // [8,3,1024]
  float* out2 = (float*)d_out + B_ * 3 * M_;      // [8,128,1024]

  // ws layout: nidx [2MB] | w0pad [17408B] | ft [~17.8MB]
  const size_t nidx_bytes = (size_t)B_ * M_ * K_ * sizeof(int);
  const size_t w0p_bytes = (size_t)64 * FTW * sizeof(float);
  const size_t ft_bytes = (size_t)B_ * N_ * FTW * sizeof(float);
  int* nidx = (int*)d_ws;
  float* w0pad = (float*)((char*)d_ws + nidx_bytes);
  float* ft = (float*)((char*)d_ws + nidx_bytes + w0p_bytes);
  const bool use_ft = ws_size >= nidx_bytes + w0p_bytes + ft_bytes;

  hipLaunchKernelGGL(fps_ft_kernel, dim3(use_ft ? 64 : 8), dim3(256), 0, stream,
                     xyz, feat, w0, w0pad, ft, nxyz);
  hipLaunchKernelGGL(ballq_kernel, dim3(B_ * M_ / 4), dim3(256), 0, stream, xyz, nxyz, nidx);
  if (use_ft) {
    hipLaunchKernelGGL(mlp_t_kernel, dim3(B_ * M_), dim3(128), 0, stream,
                       ft, w0pad, nidx, nxyz, s0, b0, w1, s1, b1, w2, s2, b2, out2);
  } else {
    hipLaunchKernelGGL(mlp_kernel_fb, dim3(B_ * M_), dim3(64), 0, stream,
                       xyz, feat, nidx, nxyz, w0, s0, b0, w1, s1, b1, w2, s2, b2, out2);
  }
}